// Round 5
// baseline (282.449 us; speedup 1.0000x reference)
//
#include <hip/hip_runtime.h>
#include <hip/hip_fp16.h>
#include <math.h>

#define NN 50000
#define NE 800000
#define NB 196            // dst buckets of 256 nodes: bucket = dst >> 8
#define FTILE 2048        // edges per histogram/fill block
#define FB 392            // histogram/fill blocks (392*2048 = 802816 >= NE)
#define GB0 782           // gemm0 blocks

typedef _Float16 v8h __attribute__((ext_vector_type(8)));
typedef float v4f __attribute__((ext_vector_type(4)));

// ---------------- K0: convert W0/W1/W2 -> fp16 transposed [n][k]; zero deg/bsum ----------------
__global__ __launch_bounds__(256) void k0_convert_zero(
    const float* __restrict__ W0, const float* __restrict__ W1,
    const float* __restrict__ W2, __half* __restrict__ W0T,
    __half* __restrict__ W1T, __half* __restrict__ W2T,
    int* __restrict__ deg, int* __restrict__ bsum) {
  int gid = blockIdx.x * 256 + threadIdx.x;   // grid 200*256 = 51200
  if (gid < NN) deg[gid] = 0;
  if (gid < 256) bsum[gid] = 0;
  if (gid < 16384) {
    int n = gid >> 7, k = gid & 127;
    W0T[gid] = __float2half(W0[k * 128 + n]);
  } else if (gid < 32768) {
    int g = gid - 16384; int n = g >> 7, k = g & 127;
    W1T[g] = __float2half(W1[k * 128 + n]);
  } else if (gid < 40960) {
    int g = gid - 32768; int n = g >> 7, k = g & 127;   // n<64, k<128
    W2T[g] = __float2half(W2[k * 64 + n]);
  }
}

// ---------------- K1: degree histogram (global atomics) + bucket sums (LDS -> 1 atomic) ----
__global__ __launch_bounds__(256) void k1_hist(
    const int* __restrict__ dst, int* __restrict__ deg, int* __restrict__ bsum) {
  __shared__ int bcnt[256];
  int tid = threadIdx.x;
  bcnt[tid] = 0;
  __syncthreads();
#pragma unroll
  for (int q = 0; q < FTILE / 1024; q++) {
    int base = blockIdx.x * FTILE + q * 1024 + tid * 4;
    if (base + 3 < NE) {
      int4 d = *(const int4*)&dst[base];
      atomicAdd(&deg[d.x], 1); atomicAdd(&bcnt[d.x >> 8], 1);
      atomicAdd(&deg[d.y], 1); atomicAdd(&bcnt[d.y >> 8], 1);
      atomicAdd(&deg[d.z], 1); atomicAdd(&bcnt[d.z >> 8], 1);
      atomicAdd(&deg[d.w], 1); atomicAdd(&bcnt[d.w >> 8], 1);
    } else {
#pragma unroll
      for (int k = 0; k < 4; k++)
        if (base + k < NE) {
          int d = dst[base + k];
          atomicAdd(&deg[d], 1);
          atomicAdd(&bcnt[d >> 8], 1);
        }
    }
  }
  __syncthreads();
  if (tid < NB && bcnt[tid] > 0) atomicAdd(&bsum[tid], bcnt[tid]);
}

// ---------------- K2: row_ptr + cursor init (196 blocks; two in-block scans) ----------------
__global__ __launch_bounds__(256) void k2_rowptr(
    const int* __restrict__ deg, const int* __restrict__ bsum,
    int* __restrict__ row_ptr, int* __restrict__ cursor) {
  int b = blockIdx.x;
  int tid = threadIdx.x;
  int lane = tid & 63, wid = tid >> 6;
  __shared__ int sbase[256];
  __shared__ int wsumA[4];
  __shared__ int wsumB[4];
  // scan 1: exclusive prefix of bucket sums -> global es base of each bucket
  int tv = (tid < NB) ? bsum[tid] : 0;
  {
    int x = tv;
#pragma unroll
    for (int o = 1; o < 64; o <<= 1) { int y = __shfl_up(x, o, 64); if (lane >= o) x += y; }
    if (lane == 63) wsumA[wid] = x;
    __syncthreads();
    int wpre = 0;
#pragma unroll
    for (int w = 0; w < 4; w++) if (w < wid) wpre += wsumA[w];
    sbase[tid] = wpre + x - tv;
  }
  __syncthreads();
  int lo = sbase[b];
  // scan 2: exclusive prefix of this bucket's degrees
  int node = (b << 8) + tid;
  int v = (node < NN) ? deg[node] : 0;
  int start;
  {
    int x = v;
#pragma unroll
    for (int o = 1; o < 64; o <<= 1) { int y = __shfl_up(x, o, 64); if (lane >= o) x += y; }
    if (lane == 63) wsumB[wid] = x;
    __syncthreads();
    int wpre = 0;
#pragma unroll
    for (int w = 0; w < 4; w++) if (w < wid) wpre += wsumB[w];
    start = lo + wpre + x - v;
  }
  if (node < NN) {
    row_ptr[node] = start;
    cursor[node] = start;
  }
  if (b == 0 && tid == 0) row_ptr[NN] = NE;
}

// ---------------- K3: edge fill (blocks >= GB0) fused with GEMM0 (blocks < GB0) -----------
// Both depend only on K0/K2 and are mutually independent -> one launch.
__global__ __launch_bounds__(256) void k3_fill_gemm0(
    const int* __restrict__ src, const int* __restrict__ dst,
    int* __restrict__ cursor, int* __restrict__ es,
    const float* __restrict__ feat, const __half* __restrict__ W0T,
    __half* __restrict__ Y) {
  const int tid = threadIdx.x;
  if (blockIdx.x >= GB0) {
    // ---- fill path: es[pos] = src byte-offset (src*256), grouped by dst via atomic cursor
    int fb = blockIdx.x - GB0;
#pragma unroll
    for (int q = 0; q < FTILE / 1024; q++) {
      int base = fb * FTILE + q * 1024 + tid * 4;
      if (base + 3 < NE) {
        int4 d = *(const int4*)&dst[base];
        int4 s = *(const int4*)&src[base];
        int p0 = atomicAdd(&cursor[d.x], 1); es[p0] = s.x << 8;
        int p1 = atomicAdd(&cursor[d.y], 1); es[p1] = s.y << 8;
        int p2 = atomicAdd(&cursor[d.z], 1); es[p2] = s.z << 8;
        int p3 = atomicAdd(&cursor[d.w], 1); es[p3] = s.w << 8;
      } else {
#pragma unroll
        for (int k = 0; k < 4; k++)
          if (base + k < NE) {
            int pp = atomicAdd(&cursor[dst[base + k]], 1);
            es[pp] = src[base + k] << 8;
          }
      }
    }
    return;
  }
  // ---- GEMM0 path: Y[64x128] = fp16(feat[64x128] f32) @ W0
  __shared__ __align__(16) __half Xs[64][136];
  __shared__ __align__(16) __half Ws[128][136];
  const int row0 = blockIdx.x * 64;
#pragma unroll
  for (int i = 0; i < 4; i++) {
    int ci = tid + 256 * i;
    int r = ci >> 4, ch = ci & 15;
    int g = row0 + r;
    float4 a0 = make_float4(0.f, 0.f, 0.f, 0.f), a1 = a0;
    if (g < NN) {
      a0 = *(const float4*)&feat[(size_t)g * 128 + ch * 8];
      a1 = *(const float4*)&feat[(size_t)g * 128 + ch * 8 + 4];
    }
    union { __half2 h2[4]; int4 i4; } u;
    u.h2[0] = __floats2half2_rn(a0.x, a0.y);
    u.h2[1] = __floats2half2_rn(a0.z, a0.w);
    u.h2[2] = __floats2half2_rn(a1.x, a1.y);
    u.h2[3] = __floats2half2_rn(a1.z, a1.w);
    *(int4*)&Xs[r][ch * 8] = u.i4;
  }
#pragma unroll
  for (int i = 0; i < 8; i++) {
    int ci = tid + 256 * i;
    int n = ci >> 4, ch = ci & 15;
    *(int4*)&Ws[n][ch * 8] = *(const int4*)&W0T[(size_t)n * 128 + ch * 8];
  }
  __syncthreads();
  const int lane = tid & 63;
  const int w = tid >> 6;
  const int c16 = lane & 15, q = lane >> 4;
  v8h a[4];
#pragma unroll
  for (int kt = 0; kt < 4; kt++)
    a[kt] = *(const v8h*)&Xs[w * 16 + c16][kt * 32 + q * 8];
  v4f acc[8];
#pragma unroll
  for (int t = 0; t < 8; t++) acc[t] = (v4f){0.f, 0.f, 0.f, 0.f};
#pragma unroll
  for (int t = 0; t < 8; t++) {
#pragma unroll
    for (int kt = 0; kt < 4; kt++) {
      v8h bfr = *(const v8h*)&Ws[t * 16 + c16][kt * 32 + q * 8];
      acc[t] = __builtin_amdgcn_mfma_f32_16x16x32_f16(a[kt], bfr, acc[t], 0, 0, 0);
    }
  }
#pragma unroll
  for (int t = 0; t < 8; t++)
#pragma unroll
    for (int r = 0; r < 4; r++)
      Xs[w * 16 + q * 4 + r][t * 16 + c16] = __float2half(acc[t][r]);
  __syncthreads();
#pragma unroll
  for (int i = 0; i < 4; i++) {
    int ci = tid + 256 * i;
    int r = ci / 16, ch = ci % 16;
    int g = row0 + r;
    if (g < NN) *(int4*)&Y[(size_t)g * 128 + ch * 8] = *(const int4*)&Xs[r][ch * 8];
  }
}

// ---------------- MFMA GEMM (layers 1,2): Y[64 x OUT] = X[64 x 128] @ W[128 x OUT] --------
template <int OUT>
__global__ __launch_bounds__(256) void gemm_mfma(
    const __half* __restrict__ X16, const __half* __restrict__ WT,
    __half* __restrict__ Y, int nrows) {
  constexpr int NT = OUT / 16;
  __shared__ __align__(16) __half Xs[64][136];
  __shared__ __align__(16) __half Ws[OUT][136];
  const int tid = threadIdx.x;
  const int row0 = blockIdx.x * 64;
#pragma unroll
  for (int i = 0; i < 4; i++) {
    int ci = tid + 256 * i;
    int r = ci >> 4, ch = ci & 15;
    int g = row0 + r;
    int4 v = make_int4(0, 0, 0, 0);
    if (g < nrows) v = *(const int4*)&X16[(size_t)g * 128 + ch * 8];
    *(int4*)&Xs[r][ch * 8] = v;
  }
#pragma unroll
  for (int i = 0; i < NT; i++) {
    int ci = tid + 256 * i;
    int n = ci >> 4, ch = ci & 15;
    *(int4*)&Ws[n][ch * 8] = *(const int4*)&WT[(size_t)n * 128 + ch * 8];
  }
  __syncthreads();
  const int lane = tid & 63;
  const int w = tid >> 6;
  const int c16 = lane & 15, q = lane >> 4;
  v8h a[4];
#pragma unroll
  for (int kt = 0; kt < 4; kt++)
    a[kt] = *(const v8h*)&Xs[w * 16 + c16][kt * 32 + q * 8];
  v4f acc[NT];
#pragma unroll
  for (int t = 0; t < NT; t++) acc[t] = (v4f){0.f, 0.f, 0.f, 0.f};
#pragma unroll
  for (int t = 0; t < NT; t++) {
#pragma unroll
    for (int kt = 0; kt < 4; kt++) {
      v8h bfr = *(const v8h*)&Ws[t * 16 + c16][kt * 32 + q * 8];
      acc[t] = __builtin_amdgcn_mfma_f32_16x16x32_f16(a[kt], bfr, acc[t], 0, 0, 0);
    }
  }
#pragma unroll
  for (int t = 0; t < NT; t++)
#pragma unroll
    for (int r = 0; r < 4; r++)
      Xs[w * 16 + q * 4 + r][t * 16 + c16] = __float2half(acc[t][r]);
  __syncthreads();
  constexpr int OCH = OUT / 8;
#pragma unroll
  for (int i = 0; i < 64 * OCH / 256; i++) {
    int ci = tid + 256 * i;
    int r = ci / OCH, ch = ci % OCH;
    int g = row0 + r;
    if (g < nrows) *(int4*)&Y[(size_t)g * OUT + ch * 8] = *(const int4*)&Xs[r][ch * 8];
  }
}

// ---------------- mean aggregation (+bias, +optional LN+ReLU) -----------
// Full-row gather (L3-served). es holds PRE-SCALED byte offsets (src*256) so per-edge
// address math is one 32-bit add. Unguarded full groups of GRP edges + one guarded tail.
// DEPTH chosen so GRP == 16 == mean degree for both F=128 and F=64 (tail stays small).
// fp16 packed accumulation; fp32 only in the epilogue.
template <int F, bool LN, bool HOUT>
__global__ __launch_bounds__(256) void agg_kernel(
    const __half* __restrict__ ft,
    const int* __restrict__ row_ptr, const int* __restrict__ es,
    const float* __restrict__ bias, const float* __restrict__ g,
    const float* __restrict__ beta, void* __restrict__ out_v, int n) {
  int gw = (blockIdx.x * blockDim.x + threadIdx.x) >> 6;
  int lane = threadIdx.x & 63;
  if (gw >= n) return;
  int b = row_ptr[gw], e = row_ptr[gw + 1];
  int deg = e - b;

  constexpr int LPR = F / 8;          // lanes per row (8 halves = 16B each)
  constexpr int EW  = 64 / LPR;       // edge streams
  constexpr int DEPTH = (F == 128) ? 4 : 2;
  constexpr int GRP = DEPTH * EW;     // 16 for both template instances
  const int sub = lane / LPR;
  const int ll  = lane % LPR;
  const int ll16 = ll * 16;
  const char* ftb = (const char*)ft;
  __half2 hacc[4];
#pragma unroll
  for (int q = 0; q < 4; q++) hacc[q] = __floats2half2_rn(0.f, 0.f);

  for (int cb = b; cb < e; cb += 64) {
    int rem = e - cb; if (rem > 64) rem = 64;
    int sn_l = 0;
    if (lane < rem) sn_l = es[cb + lane];   // byte offset src*256
    int nfull = rem & ~(GRP - 1);
    for (int j = 0; j < nfull; j += GRP) {
      int o[DEPTH];
#pragma unroll
      for (int d = 0; d < DEPTH; d++) {
        o[d] = __shfl(sn_l, j + d * EW + sub, 64);
        if (F == 64) o[d] >>= 1;
      }
      union { float4 f4; __half2 h2[4]; } u[DEPTH];
#pragma unroll
      for (int d = 0; d < DEPTH; d++)
        u[d].f4 = *(const float4*)(ftb + (unsigned)(o[d] + ll16));
#pragma unroll
      for (int d = 0; d < DEPTH; d++)
#pragma unroll
        for (int q = 0; q < 4; q++) hacc[q] = __hadd2(hacc[q], u[d].h2[q]);
    }
    if (nfull < rem) {
      int j = nfull;
      int jj[DEPTH], o[DEPTH];
#pragma unroll
      for (int d = 0; d < DEPTH; d++) {
        jj[d] = j + d * EW + sub;
        o[d] = __shfl(sn_l, jj[d] & 63, 64);
        if (F == 64) o[d] >>= 1;
      }
      union { float4 f4; __half2 h2[4]; } u[DEPTH];
#pragma unroll
      for (int d = 0; d < DEPTH; d++) {
        u[d].f4 = make_float4(0.f, 0.f, 0.f, 0.f);
        if (jj[d] < rem) u[d].f4 = *(const float4*)(ftb + (unsigned)(o[d] + ll16));
      }
#pragma unroll
      for (int d = 0; d < DEPTH; d++)
#pragma unroll
        for (int q = 0; q < 4; q++) hacc[q] = __hadd2(hacc[q], u[d].h2[q]);
    }
  }

  // combine the EW edge streams (packed shfl over 'sub' lane bits)
#pragma unroll
  for (int o = 32; o >= LPR; o >>= 1) {
#pragma unroll
    for (int q = 0; q < 4; q++) {
      union { __half2 h; int i; } a, s;
      a.h = hacc[q];
      s.i = __shfl_xor(a.i, o, 64);
      hacc[q] = __hadd2(a.h, s.h);
    }
  }

  float acc[8];
#pragma unroll
  for (int q = 0; q < 4; q++) {
    float2 f = __half22float2(hacc[q]);
    acc[2 * q + 0] = f.x;
    acc[2 * q + 1] = f.y;
  }

  float sc = (deg > 0) ? (1.0f / (float)deg) : 0.f;
  float4 b4a = *(const float4*)&bias[ll * 8 + 0];
  float4 b4b = *(const float4*)&bias[ll * 8 + 4];
  acc[0] = fmaf(acc[0], sc, b4a.x); acc[1] = fmaf(acc[1], sc, b4a.y);
  acc[2] = fmaf(acc[2], sc, b4a.z); acc[3] = fmaf(acc[3], sc, b4a.w);
  acc[4] = fmaf(acc[4], sc, b4b.x); acc[5] = fmaf(acc[5], sc, b4b.y);
  acc[6] = fmaf(acc[6], sc, b4b.z); acc[7] = fmaf(acc[7], sc, b4b.w);

  if (LN) {
    float sum = 0.f;
#pragma unroll
    for (int q = 0; q < 8; q++) sum += acc[q];
#pragma unroll
    for (int o = LPR / 2; o > 0; o >>= 1) sum += __shfl_xor(sum, o, 64);
    float mean = sum * (1.0f / 128.0f);
    float var = 0.f;
#pragma unroll
    for (int q = 0; q < 8; q++) { acc[q] -= mean; var = fmaf(acc[q], acc[q], var); }
#pragma unroll
    for (int o = LPR / 2; o > 0; o >>= 1) var += __shfl_xor(var, o, 64);
    float r = rsqrtf(var * (1.0f / 128.0f) + 1e-5f);
    float4 g4a = *(const float4*)&g[ll * 8 + 0];
    float4 g4b = *(const float4*)&g[ll * 8 + 4];
    float4 be4a = *(const float4*)&beta[ll * 8 + 0];
    float4 be4b = *(const float4*)&beta[ll * 8 + 4];
    acc[0] = fmaxf(acc[0] * r * g4a.x + be4a.x, 0.f);
    acc[1] = fmaxf(acc[1] * r * g4a.y + be4a.y, 0.f);
    acc[2] = fmaxf(acc[2] * r * g4a.z + be4a.z, 0.f);
    acc[3] = fmaxf(acc[3] * r * g4a.w + be4a.w, 0.f);
    acc[4] = fmaxf(acc[4] * r * g4b.x + be4b.x, 0.f);
    acc[5] = fmaxf(acc[5] * r * g4b.y + be4b.y, 0.f);
    acc[6] = fmaxf(acc[6] * r * g4b.z + be4b.z, 0.f);
    acc[7] = fmaxf(acc[7] * r * g4b.w + be4b.w, 0.f);
  }
  if (sub == 0) {
    if (HOUT) {
      __half* outh = (__half*)out_v;
      union { __half2 h2[4]; int4 i4; } u;
      u.h2[0] = __floats2half2_rn(acc[0], acc[1]);
      u.h2[1] = __floats2half2_rn(acc[2], acc[3]);
      u.h2[2] = __floats2half2_rn(acc[4], acc[5]);
      u.h2[3] = __floats2half2_rn(acc[6], acc[7]);
      *(int4*)&outh[(size_t)gw * F + ll * 8] = u.i4;
    } else {
      float* outf = (float*)out_v;
      *(float4*)&outf[(size_t)gw * F + ll * 8 + 0] = make_float4(acc[0], acc[1], acc[2], acc[3]);
      *(float4*)&outf[(size_t)gw * F + ll * 8 + 4] = make_float4(acc[4], acc[5], acc[6], acc[7]);
    }
  }
}

// ---------------- orchestration ----------------
extern "C" void kernel_launch(void* const* d_in, const int* in_sizes, int n_in,
                              void* d_out, int out_size, void* d_ws, size_t ws_size,
                              hipStream_t stream) {
  (void)in_sizes; (void)n_in; (void)out_size; (void)ws_size;
  const float* feat = (const float*)d_in[0];
  const int* src = (const int*)d_in[1];
  const int* dst = (const int*)d_in[2];
  const float* W0 = (const float*)d_in[3];
  const float* b0 = (const float*)d_in[4];
  const float* W1 = (const float*)d_in[5];
  const float* b1 = (const float*)d_in[6];
  const float* W2 = (const float*)d_in[7];
  const float* b2 = (const float*)d_in[8];
  const float* ln1g = (const float*)d_in[9];
  const float* ln1b = (const float*)d_in[10];
  const float* ln2g = (const float*)d_in[11];
  const float* ln2b = (const float*)d_in[12];
  float* out = (float*)d_out;

  char* p = (char*)d_ws;
  auto alloc = [&](size_t bytes) {
    char* r = p;
    p += (bytes + 255) & ~size_t(255);
    return r;
  };
  __half* fth      = (__half*)alloc((size_t)NN * 128 * 2);
  __half* hh       = (__half*)alloc((size_t)NN * 128 * 2);
  __half* W0T      = (__half*)alloc(128 * 128 * 2);
  __half* W1T      = (__half*)alloc(128 * 128 * 2);
  __half* W2T      = (__half*)alloc(64 * 128 * 2);
  int* row_ptr     = (int*)alloc((size_t)(NN + 1) * 4);
  int* es          = (int*)alloc((size_t)NE * 4);
  int* deg         = (int*)alloc((size_t)NN * 4);
  int* cursor      = (int*)alloc((size_t)NN * 4);
  int* bsum        = (int*)alloc(256 * 4);

  // K0: weight convert + zero counters
  k0_convert_zero<<<200, 256, 0, stream>>>(W0, W1, W2, W0T, W1T, W2T, deg, bsum);
  // K1: degree + bucket histograms
  k1_hist<<<FB, 256, 0, stream>>>(dst, deg, bsum);
  // K2: row_ptr + cursor
  k2_rowptr<<<NB, 256, 0, stream>>>(deg, bsum, row_ptr, cursor);
  // K3: edge fill || GEMM0 (one launch)
  k3_fill_gemm0<<<GB0 + FB, 256, 0, stream>>>(src, dst, cursor, es, feat, W0T, fth);

  int gb = (NN + 63) / 64;     // 782
  int nwb = (NN + 3) / 4;

  agg_kernel<128, true, true><<<nwb, 256, 0, stream>>>(fth, row_ptr, es, b0, ln1g, ln1b, hh, NN);
  gemm_mfma<128><<<gb, 256, 0, stream>>>(hh, W1T, fth, NN);
  agg_kernel<128, true, true><<<nwb, 256, 0, stream>>>(fth, row_ptr, es, b1, ln2g, ln2b, hh, NN);
  gemm_mfma<64><<<gb, 256, 0, stream>>>(hh, W2T, fth, NN);
  agg_kernel<64, false, false><<<nwb, 256, 0, stream>>>(fth, row_ptr, es, b2, nullptr, nullptr, out, NN);
}

// Round 6
// 216.428 us; speedup vs baseline: 1.3050x; 1.3050x over previous
//
#include <hip/hip_runtime.h>
#include <hip/hip_fp16.h>
#include <math.h>

#define NN 50000
#define NE 800000
#define NB 196            // dst buckets of 256 nodes: bucket = dst >> 8
#define CPAD 16           // pad global atomic counters to one per 64B line
#define STILE 4096        // edges per stage block
#define BCAP 8192         // staged slots per bucket (avg occupancy 4081, Binomial std ~64)
#define GB0 782           // gemm0 blocks in the fused launch

typedef _Float16 v8h __attribute__((ext_vector_type(8)));
typedef float v4f __attribute__((ext_vector_type(4)));

// ---------------- convert: W0/W1/W2 -> fp16 transposed [n][k]; also zeros bhist ----------------
__global__ __launch_bounds__(256) void convert_kernel(
    const float* __restrict__ W0, const float* __restrict__ W1,
    const float* __restrict__ W2, __half* __restrict__ W0T,
    __half* __restrict__ W1T, __half* __restrict__ W2T,
    int* __restrict__ bhist) {
  int gid = blockIdx.x * 256 + threadIdx.x;
  if (gid < NB * CPAD) bhist[gid] = 0;
  if (gid < 16384) {
    int n = gid >> 7, k = gid & 127;
    W0T[gid] = __float2half(W0[k * 128 + n]);
  } else if (gid < 32768) {
    int g = gid - 16384; int n = g >> 7, k = g & 127;
    W1T[g] = __float2half(W1[k * 128 + n]);
  } else if (gid < 40960) {
    int g = gid - 32768; int n = g >> 7, k = g & 127;   // n<64, k<128
    W2T[g] = __float2half(W2[k * 64 + n]);
  }
}

// ---------------- stage: LDS hist -> 1 global atomic per (block,bucket) -> bucket scatter ----
__global__ __launch_bounds__(256) void stage_kernel(const int* __restrict__ src,
                                                    const int* __restrict__ dst,
                                                    int* __restrict__ bhist,
                                                    int* __restrict__ staged) {
  __shared__ int cnt[256];
  __shared__ int basep[256];
  __shared__ int cur[256];
  int tid = threadIdx.x;
  cnt[tid] = 0;
  cur[tid] = 0;
  __syncthreads();
#pragma unroll
  for (int q = 0; q < 4; q++) {
    int base = blockIdx.x * STILE + q * 1024 + tid * 4;
    if (base + 3 < NE) {
      int4 d = *(const int4*)&dst[base];
      atomicAdd(&cnt[d.x >> 8], 1);
      atomicAdd(&cnt[d.y >> 8], 1);
      atomicAdd(&cnt[d.z >> 8], 1);
      atomicAdd(&cnt[d.w >> 8], 1);
    } else {
#pragma unroll
      for (int k = 0; k < 4; k++)
        if (base + k < NE) atomicAdd(&cnt[dst[base + k] >> 8], 1);
    }
  }
  __syncthreads();
  if (tid < NB) basep[tid] = (cnt[tid] > 0) ? atomicAdd(&bhist[tid * CPAD], cnt[tid]) : 0;
  __syncthreads();
#pragma unroll
  for (int q = 0; q < 4; q++) {
    int base = blockIdx.x * STILE + q * 1024 + tid * 4;
    if (base + 3 < NE) {
      int4 d = *(const int4*)&dst[base];
      int4 s = *(const int4*)&src[base];
      int b0 = d.x >> 8, b1 = d.y >> 8, b2 = d.z >> 8, b3 = d.w >> 8;
      int p0 = atomicAdd(&cur[b0], 1);
      staged[b0 * BCAP + basep[b0] + p0] = s.x | ((d.x & 255) << 16);
      int p1 = atomicAdd(&cur[b1], 1);
      staged[b1 * BCAP + basep[b1] + p1] = s.y | ((d.y & 255) << 16);
      int p2 = atomicAdd(&cur[b2], 1);
      staged[b2 * BCAP + basep[b2] + p2] = s.z | ((d.z & 255) << 16);
      int p3 = atomicAdd(&cur[b3], 1);
      staged[b3 * BCAP + basep[b3] + p3] = s.w | ((d.w & 255) << 16);
    } else {
#pragma unroll
      for (int k = 0; k < 4; k++) {
        if (base + k < NE) {
          int d = dst[base + k], s = src[base + k];
          int bb = d >> 8;
          int pp = atomicAdd(&cur[bb], 1);
          staged[bb * BCAP + basep[bb] + pp] = s | ((d & 255) << 16);
        }
      }
    }
  }
}

// ---------------- fused: bucket-CSR (blocks 0..NB-1) || GEMM0 (blocks NB..NB+GB0-1) --------
// Mutually independent (bucket needs stage; gemm0 needs convert) -> one launch, the ~10us
// CSR ordering pass hides behind the HBM-bound GEMM0. Both bodies verbatim from round 4.
__global__ __launch_bounds__(256) void bucket_gemm0_fused(
    const int* __restrict__ staged, const int* __restrict__ bhist,
    int* __restrict__ row_ptr, int* __restrict__ es,
    const float* __restrict__ feat, const __half* __restrict__ W0T,
    __half* __restrict__ Y) {
  __shared__ __align__(16) union {
    struct { __half Xs[64][136]; __half Ws[128][136]; } g;
    struct { int sbase[256]; int wsum[4]; int cnt[256]; int fill_l[256]; } c;
  } sh;
  const int tid = threadIdx.x;

  if (blockIdx.x >= NB) {
    // ---- GEMM0: Y[64x128] = fp16(feat[64x128] f32) @ W0  (identical to gemm_mfma<128,true>)
    const int row0 = (blockIdx.x - NB) * 64;
#pragma unroll
    for (int i = 0; i < 4; i++) {
      int ci = tid + 256 * i;
      int r = ci >> 4, ch = ci & 15;
      int g = row0 + r;
      float4 a0 = make_float4(0.f, 0.f, 0.f, 0.f), a1 = a0;
      if (g < NN) {
        a0 = *(const float4*)&feat[(size_t)g * 128 + ch * 8];
        a1 = *(const float4*)&feat[(size_t)g * 128 + ch * 8 + 4];
      }
      union { __half2 h2[4]; int4 i4; } u;
      u.h2[0] = __floats2half2_rn(a0.x, a0.y);
      u.h2[1] = __floats2half2_rn(a0.z, a0.w);
      u.h2[2] = __floats2half2_rn(a1.x, a1.y);
      u.h2[3] = __floats2half2_rn(a1.z, a1.w);
      *(int4*)&sh.g.Xs[r][ch * 8] = u.i4;
    }
#pragma unroll
    for (int i = 0; i < 8; i++) {
      int ci = tid + 256 * i;
      int n = ci >> 4, ch = ci & 15;
      *(int4*)&sh.g.Ws[n][ch * 8] = *(const int4*)&W0T[(size_t)n * 128 + ch * 8];
    }
    __syncthreads();
    const int lane = tid & 63;
    const int w = tid >> 6;
    const int c16 = lane & 15, q = lane >> 4;
    v8h a[4];
#pragma unroll
    for (int kt = 0; kt < 4; kt++)
      a[kt] = *(const v8h*)&sh.g.Xs[w * 16 + c16][kt * 32 + q * 8];
    v4f acc[8];
#pragma unroll
    for (int t = 0; t < 8; t++) acc[t] = (v4f){0.f, 0.f, 0.f, 0.f};
#pragma unroll
    for (int t = 0; t < 8; t++) {
#pragma unroll
      for (int kt = 0; kt < 4; kt++) {
        v8h bfr = *(const v8h*)&sh.g.Ws[t * 16 + c16][kt * 32 + q * 8];
        acc[t] = __builtin_amdgcn_mfma_f32_16x16x32_f16(a[kt], bfr, acc[t], 0, 0, 0);
      }
    }
#pragma unroll
    for (int t = 0; t < 8; t++)
#pragma unroll
      for (int r = 0; r < 4; r++)
        sh.g.Xs[w * 16 + q * 4 + r][t * 16 + c16] = __float2half(acc[t][r]);
    __syncthreads();
#pragma unroll
    for (int i = 0; i < 4; i++) {
      int ci = tid + 256 * i;
      int r = ci / 16, ch = ci % 16;
      int g = row0 + r;
      if (g < NN) *(int4*)&Y[(size_t)g * 128 + ch * 8] = *(const int4*)&sh.g.Xs[r][ch * 8];
    }
    return;
  }

  // ---- bucket-CSR: order this bucket's staged edges -> row_ptr + es (verbatim round 4)
  int b = blockIdx.x;
  int lane = tid & 63, wid = tid >> 6;
  int tv = (tid < NB) ? bhist[tid * CPAD] : 0;
  int x = tv;
#pragma unroll
  for (int o = 1; o < 64; o <<= 1) {
    int y = __shfl_up(x, o, 64);
    if (lane >= o) x += y;
  }
  if (lane == 63) sh.c.wsum[wid] = x;
  __syncthreads();
  int wpre = 0;
  for (int w = 0; w < wid; w++) wpre += sh.c.wsum[w];
  sh.c.sbase[tid] = wpre + x - tv;
  sh.c.cnt[tid] = 0;
  __syncthreads();
  int lo = sh.c.sbase[b];
  int cntb = bhist[b * CPAD];
  const int* st = &staged[b * BCAP];
  for (int i = tid; i < cntb; i += 256)
    atomicAdd(&sh.c.cnt[(st[i] >> 16) & 255], 1);
  __syncthreads();
  int v = sh.c.cnt[tid];
  x = v;
#pragma unroll
  for (int o = 1; o < 64; o <<= 1) {
    int y = __shfl_up(x, o, 64);
    if (lane >= o) x += y;
  }
  __syncthreads();
  if (lane == 63) sh.c.wsum[wid] = x;
  __syncthreads();
  wpre = 0;
  for (int w = 0; w < wid; w++) wpre += sh.c.wsum[w];
  int start = lo + wpre + x - v;
  int node = (b << 8) + tid;
  if (node < NN) row_ptr[node] = start;
  sh.c.fill_l[tid] = start;
  __syncthreads();
  for (int i = tid; i < cntb; i += 256) {
    int w = st[i];
    int pos = atomicAdd(&sh.c.fill_l[(w >> 16) & 255], 1);
    es[pos] = (w & 0xFFFF) << 8;    // pre-scaled byte offset (src * 256)
  }
  if (b == 0 && tid == 0) row_ptr[NN] = NE;
}

// ---------------- MFMA GEMM (layers 1,2): Y[64 x OUT] = X[64 x 128] @ W[128 x OUT] --------
template <int OUT>
__global__ __launch_bounds__(256) void gemm_mfma(
    const __half* __restrict__ X16, const __half* __restrict__ WT,
    __half* __restrict__ Y, int nrows) {
  constexpr int NT = OUT / 16;
  __shared__ __align__(16) __half Xs[64][136];
  __shared__ __align__(16) __half Ws[OUT][136];
  const int tid = threadIdx.x;
  const int row0 = blockIdx.x * 64;
#pragma unroll
  for (int i = 0; i < 4; i++) {
    int ci = tid + 256 * i;
    int r = ci >> 4, ch = ci & 15;
    int g = row0 + r;
    int4 v = make_int4(0, 0, 0, 0);
    if (g < nrows) v = *(const int4*)&X16[(size_t)g * 128 + ch * 8];
    *(int4*)&Xs[r][ch * 8] = v;
  }
#pragma unroll
  for (int i = 0; i < NT; i++) {
    int ci = tid + 256 * i;
    int n = ci >> 4, ch = ci & 15;
    *(int4*)&Ws[n][ch * 8] = *(const int4*)&WT[(size_t)n * 128 + ch * 8];
  }
  __syncthreads();
  const int lane = tid & 63;
  const int w = tid >> 6;
  const int c16 = lane & 15, q = lane >> 4;
  v8h a[4];
#pragma unroll
  for (int kt = 0; kt < 4; kt++)
    a[kt] = *(const v8h*)&Xs[w * 16 + c16][kt * 32 + q * 8];
  v4f acc[NT];
#pragma unroll
  for (int t = 0; t < NT; t++) acc[t] = (v4f){0.f, 0.f, 0.f, 0.f};
#pragma unroll
  for (int t = 0; t < NT; t++) {
#pragma unroll
    for (int kt = 0; kt < 4; kt++) {
      v8h bfr = *(const v8h*)&Ws[t * 16 + c16][kt * 32 + q * 8];
      acc[t] = __builtin_amdgcn_mfma_f32_16x16x32_f16(a[kt], bfr, acc[t], 0, 0, 0);
    }
  }
#pragma unroll
  for (int t = 0; t < NT; t++)
#pragma unroll
    for (int r = 0; r < 4; r++)
      Xs[w * 16 + q * 4 + r][t * 16 + c16] = __float2half(acc[t][r]);
  __syncthreads();
  constexpr int OCH = OUT / 8;
#pragma unroll
  for (int i = 0; i < 64 * OCH / 256; i++) {
    int ci = tid + 256 * i;
    int r = ci / OCH, ch = ci % OCH;
    int g = row0 + r;
    if (g < nrows) *(int4*)&Y[(size_t)g * OUT + ch * 8] = *(const int4*)&Xs[r][ch * 8];
  }
}

// ---------------- mean aggregation (+bias, +optional LN+ReLU) -----------
// Full-row gather (L3-served). es holds PRE-SCALED byte offsets (src*256) so per-edge
// address math is one 32-bit add. Unguarded full groups of GRP edges + one guarded tail.
// DEPTH chosen so GRP == 16 == mean degree for both F=128 and F=64.
// fp16 packed accumulation; fp32 only in the epilogue.
template <int F, bool LN, bool HOUT>
__global__ __launch_bounds__(256) void agg_kernel(
    const __half* __restrict__ ft,
    const int* __restrict__ row_ptr, const int* __restrict__ es,
    const float* __restrict__ bias, const float* __restrict__ g,
    const float* __restrict__ beta, void* __restrict__ out_v, int n) {
  int gw = (blockIdx.x * blockDim.x + threadIdx.x) >> 6;
  int lane = threadIdx.x & 63;
  if (gw >= n) return;
  int b = row_ptr[gw], e = row_ptr[gw + 1];
  int deg = e - b;

  constexpr int LPR = F / 8;          // lanes per row (8 halves = 16B each)
  constexpr int EW  = 64 / LPR;       // edge streams
  constexpr int DEPTH = (F == 128) ? 4 : 2;
  constexpr int GRP = DEPTH * EW;     // 16 for both template instances
  const int sub = lane / LPR;
  const int ll  = lane % LPR;
  const int ll16 = ll * 16;
  const char* ftb = (const char*)ft;
  __half2 hacc[4];
#pragma unroll
  for (int q = 0; q < 4; q++) hacc[q] = __floats2half2_rn(0.f, 0.f);

  for (int cb = b; cb < e; cb += 64) {
    int rem = e - cb; if (rem > 64) rem = 64;
    int sn_l = 0;
    if (lane < rem) sn_l = es[cb + lane];   // byte offset src*256
    int nfull = rem & ~(GRP - 1);
    for (int j = 0; j < nfull; j += GRP) {
      int o[DEPTH];
#pragma unroll
      for (int d = 0; d < DEPTH; d++) {
        o[d] = __shfl(sn_l, j + d * EW + sub, 64);
        if (F == 64) o[d] >>= 1;
      }
      union { float4 f4; __half2 h2[4]; } u[DEPTH];
#pragma unroll
      for (int d = 0; d < DEPTH; d++)
        u[d].f4 = *(const float4*)(ftb + (unsigned)(o[d] + ll16));
#pragma unroll
      for (int d = 0; d < DEPTH; d++)
#pragma unroll
        for (int q = 0; q < 4; q++) hacc[q] = __hadd2(hacc[q], u[d].h2[q]);
    }
    if (nfull < rem) {
      int j = nfull;
      int jj[DEPTH], o[DEPTH];
#pragma unroll
      for (int d = 0; d < DEPTH; d++) {
        jj[d] = j + d * EW + sub;
        o[d] = __shfl(sn_l, jj[d] & 63, 64);
        if (F == 64) o[d] >>= 1;
      }
      union { float4 f4; __half2 h2[4]; } u[DEPTH];
#pragma unroll
      for (int d = 0; d < DEPTH; d++) {
        u[d].f4 = make_float4(0.f, 0.f, 0.f, 0.f);
        if (jj[d] < rem) u[d].f4 = *(const float4*)(ftb + (unsigned)(o[d] + ll16));
      }
#pragma unroll
      for (int d = 0; d < DEPTH; d++)
#pragma unroll
        for (int q = 0; q < 4; q++) hacc[q] = __hadd2(hacc[q], u[d].h2[q]);
    }
  }

  // combine the EW edge streams (packed shfl over 'sub' lane bits)
#pragma unroll
  for (int o = 32; o >= LPR; o >>= 1) {
#pragma unroll
    for (int q = 0; q < 4; q++) {
      union { __half2 h; int i; } a, s;
      a.h = hacc[q];
      s.i = __shfl_xor(a.i, o, 64);
      hacc[q] = __hadd2(a.h, s.h);
    }
  }

  float acc[8];
#pragma unroll
  for (int q = 0; q < 4; q++) {
    float2 f = __half22float2(hacc[q]);
    acc[2 * q + 0] = f.x;
    acc[2 * q + 1] = f.y;
  }

  float sc = (deg > 0) ? (1.0f / (float)deg) : 0.f;
  float4 b4a = *(const float4*)&bias[ll * 8 + 0];
  float4 b4b = *(const float4*)&bias[ll * 8 + 4];
  acc[0] = fmaf(acc[0], sc, b4a.x); acc[1] = fmaf(acc[1], sc, b4a.y);
  acc[2] = fmaf(acc[2], sc, b4a.z); acc[3] = fmaf(acc[3], sc, b4a.w);
  acc[4] = fmaf(acc[4], sc, b4b.x); acc[5] = fmaf(acc[5], sc, b4b.y);
  acc[6] = fmaf(acc[6], sc, b4b.z); acc[7] = fmaf(acc[7], sc, b4b.w);

  if (LN) {
    float sum = 0.f;
#pragma unroll
    for (int q = 0; q < 8; q++) sum += acc[q];
#pragma unroll
    for (int o = LPR / 2; o > 0; o >>= 1) sum += __shfl_xor(sum, o, 64);
    float mean = sum * (1.0f / 128.0f);
    float var = 0.f;
#pragma unroll
    for (int q = 0; q < 8; q++) { acc[q] -= mean; var = fmaf(acc[q], acc[q], var); }
#pragma unroll
    for (int o = LPR / 2; o > 0; o >>= 1) var += __shfl_xor(var, o, 64);
    float r = rsqrtf(var * (1.0f / 128.0f) + 1e-5f);
    float4 g4a = *(const float4*)&g[ll * 8 + 0];
    float4 g4b = *(const float4*)&g[ll * 8 + 4];
    float4 be4a = *(const float4*)&beta[ll * 8 + 0];
    float4 be4b = *(const float4*)&beta[ll * 8 + 4];
    acc[0] = fmaxf(acc[0] * r * g4a.x + be4a.x, 0.f);
    acc[1] = fmaxf(acc[1] * r * g4a.y + be4a.y, 0.f);
    acc[2] = fmaxf(acc[2] * r * g4a.z + be4a.z, 0.f);
    acc[3] = fmaxf(acc[3] * r * g4a.w + be4a.w, 0.f);
    acc[4] = fmaxf(acc[4] * r * g4b.x + be4b.x, 0.f);
    acc[5] = fmaxf(acc[5] * r * g4b.y + be4b.y, 0.f);
    acc[6] = fmaxf(acc[6] * r * g4b.z + be4b.z, 0.f);
    acc[7] = fmaxf(acc[7] * r * g4b.w + be4b.w, 0.f);
  }
  if (sub == 0) {
    if (HOUT) {
      __half* outh = (__half*)out_v;
      union { __half2 h2[4]; int4 i4; } u;
      u.h2[0] = __floats2half2_rn(acc[0], acc[1]);
      u.h2[1] = __floats2half2_rn(acc[2], acc[3]);
      u.h2[2] = __floats2half2_rn(acc[4], acc[5]);
      u.h2[3] = __floats2half2_rn(acc[6], acc[7]);
      *(int4*)&outh[(size_t)gw * F + ll * 8] = u.i4;
    } else {
      float* outf = (float*)out_v;
      *(float4*)&outf[(size_t)gw * F + ll * 8 + 0] = make_float4(acc[0], acc[1], acc[2], acc[3]);
      *(float4*)&outf[(size_t)gw * F + ll * 8 + 4] = make_float4(acc[4], acc[5], acc[6], acc[7]);
    }
  }
}

// ---------------- orchestration ----------------
extern "C" void kernel_launch(void* const* d_in, const int* in_sizes, int n_in,
                              void* d_out, int out_size, void* d_ws, size_t ws_size,
                              hipStream_t stream) {
  (void)in_sizes; (void)n_in; (void)out_size; (void)ws_size;
  const float* feat = (const float*)d_in[0];
  const int* src = (const int*)d_in[1];
  const int* dst = (const int*)d_in[2];
  const float* W0 = (const float*)d_in[3];
  const float* b0 = (const float*)d_in[4];
  const float* W1 = (const float*)d_in[5];
  const float* b1 = (const float*)d_in[6];
  const float* W2 = (const float*)d_in[7];
  const float* b2 = (const float*)d_in[8];
  const float* ln1g = (const float*)d_in[9];
  const float* ln1b = (const float*)d_in[10];
  const float* ln2g = (const float*)d_in[11];
  const float* ln2b = (const float*)d_in[12];
  float* out = (float*)d_out;

  char* p = (char*)d_ws;
  auto alloc = [&](size_t bytes) {
    char* r = p;
    p += (bytes + 255) & ~size_t(255);
    return r;
  };
  __half* fth      = (__half*)alloc((size_t)NN * 128 * 2);
  __half* hh       = (__half*)alloc((size_t)NN * 128 * 2);
  __half* W0T      = (__half*)alloc(128 * 128 * 2);
  __half* W1T      = (__half*)alloc(128 * 128 * 2);
  __half* W2T      = (__half*)alloc(64 * 128 * 2);
  int* row_ptr     = (int*)alloc((size_t)(NN + 1) * 4);
  int* es          = (int*)alloc((size_t)NE * 4);
  int* staged      = (int*)alloc((size_t)NB * BCAP * 4);
  int* bhist       = (int*)alloc((size_t)NB * CPAD * 4);

  // convert weights + zero bhist
  convert_kernel<<<160, 256, 0, stream>>>(W0, W1, W2, W0T, W1T, W2T, bhist);

  // stage edges into dst buckets
  int sb = (NE + STILE - 1) / STILE;   // 196 blocks
  stage_kernel<<<sb, 256, 0, stream>>>(src, dst, bhist, staged);

  // bucket-CSR || GEMM0 in one launch (mutually independent)
  bucket_gemm0_fused<<<NB + GB0, 256, 0, stream>>>(staged, bhist, row_ptr, es, feat, W0T, fth);

  int gb = (NN + 63) / 64;     // 782
  int nwb = (NN + 3) / 4;

  agg_kernel<128, true, true><<<nwb, 256, 0, stream>>>(fth, row_ptr, es, b0, ln1g, ln1b, hh, NN);
  gemm_mfma<128><<<gb, 256, 0, stream>>>(hh, W1T, fth, NN);
  agg_kernel<128, true, true><<<nwb, 256, 0, stream>>>(fth, row_ptr, es, b1, ln2g, ln2b, hh, NN);
  gemm_mfma<64><<<gb, 256, 0, stream>>>(hh, W2T, fth, NN);
  agg_kernel<64, false, false><<<nwb, 256, 0, stream>>>(fth, row_ptr, es, b2, nullptr, nullptr, out, NN);
}